// Round 7
// baseline (236.711 us; speedup 1.0000x reference)
//
#include <hip/hip_runtime.h>
#include <math.h>

typedef __attribute__((ext_vector_type(8))) short bf16x8;
typedef __attribute__((ext_vector_type(4))) float f32x4;
typedef __attribute__((ext_vector_type(16))) float f32x16;

#define S_LEN 2048
#define DH 64
#define NHEAD 64
#define HEAD_ELEMS (S_LEN * DH)
#define NT (S_LEN / 64)

static __device__ __forceinline__ unsigned short f2bf(float f) {
  union { float f; unsigned u; } v; v.f = f;
  return (unsigned short)((v.u + 0x7fffu + ((v.u >> 16) & 1u)) >> 16);
}

// ---------------- pre-pass: repack K and V into MFMA-fragment-major bf16 ----------------
// A "chunk" = 1 KB = one wave's global_load_dwordx4 (lane l -> bytes l*16..+15).
// K chunk (per head) idx (kt*8 + t*4 + d):        lane l holds K[kt*64+t*32+(l&31)][d*16+(l>>5)*8 + 0..7]
// V chunk (per head) idx (kt*8 + t*4 + kh*2 + eh): lane l holds V^T[eh*32+(l&31)][kt*64+t*32+kh*16+(l>>5)*8 + 0..7]
__global__ __launch_bounds__(256)
void prep(const float* __restrict__ k, const float* __restrict__ v,
          unsigned short* __restrict__ ko, unsigned short* __restrict__ vt) {
  __shared__ float t[64][65];
  const int tid = threadIdx.x;
  if (blockIdx.x < 2048) {
    // K repack: one 64x64 tile (head, kt) per block
    const int head = blockIdx.x >> 5;
    const int kt   = blockIdx.x & 31;
    const float* kp = k + (size_t)head * HEAD_ELEMS;
    unsigned short* kout = ko + (size_t)head * HEAD_ELEMS + (size_t)kt * 4096;
    #pragma unroll
    for (int i = 0; i < 2; ++i) {
      const int c     = i * 256 + tid;      // 0..511
      const int chunk = c >> 6;             // 0..7 : t*4 + d
      const int tt    = chunk >> 2;
      const int d     = chunk & 3;
      const int l     = c & 63;
      const int row   = kt * 64 + tt * 32 + (l & 31);
      const int col   = d * 16 + (l >> 5) * 8;
      const float* src = kp + (size_t)row * DH + col;
      float4 a = *(const float4*)src;
      float4 b = *(const float4*)(src + 4);
      bf16x8 r;
      r[0]=(short)f2bf(a.x); r[1]=(short)f2bf(a.y); r[2]=(short)f2bf(a.z); r[3]=(short)f2bf(a.w);
      r[4]=(short)f2bf(b.x); r[5]=(short)f2bf(b.y); r[6]=(short)f2bf(b.z); r[7]=(short)f2bf(b.w);
      *(bf16x8*)(kout + (size_t)chunk * 512 + l * 8) = r;
    }
  } else {
    // V transpose + repack: one 64x64 tile (head, kc) per block
    const int bi   = blockIdx.x - 2048;
    const int head = bi >> 5;
    const int kc   = bi & 31;
    const float* vp = v + (size_t)head * HEAD_ELEMS + (size_t)kc * 64 * DH;
    #pragma unroll
    for (int i = 0; i < 4; ++i) {
      int fi = tid + i * 256;
      int kk = fi >> 4, e4 = (fi & 15) * 4;
      float4 f = *(const float4*)(vp + kk * DH + e4);
      t[kk][e4] = f.x; t[kk][e4+1] = f.y; t[kk][e4+2] = f.z; t[kk][e4+3] = f.w;
    }
    __syncthreads();
    unsigned short* vout = vt + (size_t)head * HEAD_ELEMS + (size_t)kc * 4096;
    #pragma unroll
    for (int i = 0; i < 2; ++i) {
      const int c     = i * 256 + tid;
      const int chunk = c >> 6;             // t2*4 + kh*2 + eh
      const int t2    = chunk >> 2;
      const int kh    = (chunk >> 1) & 1;
      const int eh    = chunk & 1;
      const int l     = c & 63;
      const int e     = eh * 32 + (l & 31);
      const int kr    = t2 * 32 + kh * 16 + (l >> 5) * 8;
      bf16x8 r;
      #pragma unroll
      for (int j = 0; j < 8; ++j) r[j] = (short)f2bf(t[kr + j][e]);
      *(bf16x8*)(vout + (size_t)chunk * 512 + l * 8) = r;
    }
  }
}

// ---------------- main: all-register, zero-barrier flash attention + projection ----------------
__global__ __launch_bounds__(256, 4)
void attn_reg(const float* __restrict__ qg, const unsigned short* __restrict__ kfb,
              const unsigned short* __restrict__ vfb, const float* __restrict__ wg,
              const float* __restrict__ bg, float* __restrict__ og) {
  __shared__ __align__(16) unsigned short Ylds[4][2048];  // 4 KB per wave (epilogue only)
  __shared__ float stats[4][32];

  const int tid = threadIdx.x;
  const int w   = tid >> 6;     // 0..3
  const int l   = tid & 63;
  const int lq  = l & 31;
  const int hi  = l >> 5;

  // XCD swizzle (1024 wgs, 8 XCDs): 8 heads' 16 blocks contiguous per XCD
  const int bxs  = ((blockIdx.x & 7) << 7) | (blockIdx.x >> 3);
  const int bh   = bxs >> 4;
  const int qblk = bxs & 15;

  const unsigned short* kh_ = kfb + (size_t)bh * HEAD_ELEMS + l * 8;
  const unsigned short* vh_ = vfb + (size_t)bh * HEAD_ELEMS + l * 8;

  // Q B-fragments from f32 global; 1/sqrt(64)*log2(e) folded in
  bf16x8 qf[4];
  {
    const float QS = 0.125f * 1.44269504f;
    const float* qfp = qg + (size_t)bh * HEAD_ELEMS
                     + (size_t)(qblk * 128 + w * 32 + lq) * DH + hi * 8;
    #pragma unroll
    for (int d = 0; d < 4; ++d) {
      float4 f0 = *(const float4*)(qfp + d * 16);
      float4 f1 = *(const float4*)(qfp + d * 16 + 4);
      bf16x8 a;
      a[0]=(short)f2bf(f0.x*QS); a[1]=(short)f2bf(f0.y*QS);
      a[2]=(short)f2bf(f0.z*QS); a[3]=(short)f2bf(f0.w*QS);
      a[4]=(short)f2bf(f1.x*QS); a[5]=(short)f2bf(f1.y*QS);
      a[6]=(short)f2bf(f1.z*QS); a[7]=(short)f2bf(f1.w*QS);
      qf[d] = a;
    }
  }

  f32x16 yacc0, yacc1, zv;
  #pragma unroll
  for (int i = 0; i < 16; ++i) { yacc0[i] = 0.f; yacc1[i] = 0.f; zv[i] = 0.f; }
  float lsum = 0.f;

  for (int kt = 0; kt < NT; ++kt) {
    #pragma unroll
    for (int t = 0; t < 2; ++t) {
      const unsigned short* kp = kh_ + (size_t)(kt * 8 + t * 4) * 512;
      const unsigned short* vp = vh_ + (size_t)(kt * 8 + t * 4) * 512;
      bf16x8 kf0 = *(const bf16x8*)(kp);
      bf16x8 kf1 = *(const bf16x8*)(kp + 512);
      bf16x8 kf2 = *(const bf16x8*)(kp + 1024);
      bf16x8 kf3 = *(const bf16x8*)(kp + 1536);
      bf16x8 v00 = *(const bf16x8*)(vp);            // kh=0, e-half 0
      bf16x8 v10 = *(const bf16x8*)(vp + 512);      // kh=0, e-half 1
      bf16x8 v01 = *(const bf16x8*)(vp + 1024);     // kh=1, e-half 0
      bf16x8 v11 = *(const bf16x8*)(vp + 1536);     // kh=1, e-half 1

      // ---- S^T = K Q^T (swapped; lane owns col q=lq, regs run over k-rows) ----
      f32x16 s;
      __builtin_amdgcn_s_setprio(1);
      s = __builtin_amdgcn_mfma_f32_32x32x16_bf16(kf0, qf[0], zv, 0, 0, 0);
      s = __builtin_amdgcn_mfma_f32_32x32x16_bf16(kf1, qf[1], s, 0, 0, 0);
      s = __builtin_amdgcn_mfma_f32_32x32x16_bf16(kf2, qf[2], s, 0, 0, 0);
      s = __builtin_amdgcn_mfma_f32_32x32x16_bf16(kf3, qf[3], s, 0, 0, 0);
      __builtin_amdgcn_s_setprio(0);

      // ---- P = exp2(s); lsum (col domain) fused; cvt_pk pairs ----
      unsigned pk[8];
      #pragma unroll
      for (int i = 0; i < 8; ++i) {
        float a = exp2f(s[2 * i]);
        float b = exp2f(s[2 * i + 1]);
        lsum += a + b;
        asm("v_cvt_pk_bf16_f32 %0, %1, %2" : "=v"(pk[i]) : "v"(a), "v"(b));
      }
      asm volatile("v_permlane32_swap_b32 %0, %1" : "+v"(pk[0]), "+v"(pk[2]));
      asm volatile("v_permlane32_swap_b32 %0, %1" : "+v"(pk[1]), "+v"(pk[3]));
      asm volatile("v_permlane32_swap_b32 %0, %1" : "+v"(pk[4]), "+v"(pk[6]));
      asm volatile("v_permlane32_swap_b32 %0, %1" : "+v"(pk[5]), "+v"(pk[7]));
      union { unsigned u[4]; bf16x8 v; } f0, f1;
      f0.u[0] = pk[0]; f0.u[1] = pk[1]; f0.u[2] = pk[2]; f0.u[3] = pk[3];
      f1.u[0] = pk[4]; f1.u[1] = pk[5]; f1.u[2] = pk[6]; f1.u[3] = pk[7];

      // ---- Y += P V ----
      __builtin_amdgcn_s_setprio(1);
      yacc0 = __builtin_amdgcn_mfma_f32_32x32x16_bf16(f0.v, v00, yacc0, 0, 0, 0);
      yacc0 = __builtin_amdgcn_mfma_f32_32x32x16_bf16(f1.v, v01, yacc0, 0, 0, 0);
      yacc1 = __builtin_amdgcn_mfma_f32_32x32x16_bf16(f0.v, v10, yacc1, 0, 0, 0);
      yacc1 = __builtin_amdgcn_mfma_f32_32x32x16_bf16(f1.v, v11, yacc1, 0, 0, 0);
      __builtin_amdgcn_s_setprio(0);
    }
  }

  // ---- lsum: col domain -> row domain via per-wave stats LDS (R3-verified) ----
  lsum += __shfl_xor(lsum, 32);
  if (hi == 0) stats[w][lq] = 1.0f / lsum;
  asm volatile("s_waitcnt lgkmcnt(0)" ::: "memory");
  __builtin_amdgcn_sched_barrier(0);

  // ---- epilogue: normalize (row-domain stats), Y -> LDS, project, bias, store ----
  {
    char* Y = (char*)Ylds[w];
    #pragma unroll
    for (int et = 0; et < 2; ++et) {
      f32x16& ya = et ? yacc1 : yacc0;
      const int e = et * 32 + lq;
      #pragma unroll
      for (int r = 0; r < 16; ++r) {
        const int qr_ = (r & 3) + 8 * (r >> 2) + 4 * hi;
        *(unsigned short*)(Y + qr_ * 128 + (((e >> 3) ^ (qr_ & 7)) << 4) + (e & 7) * 2)
            = f2bf(ya[r] * stats[w][qr_]);
      }
    }
  }
  asm volatile("s_waitcnt lgkmcnt(0)" ::: "memory");
  __builtin_amdgcn_sched_barrier(0);

  f32x16 o0, o1;
  #pragma unroll
  for (int i = 0; i < 16; ++i) { o0[i] = 0.f; o1[i] = 0.f; }
  {
    const char* Y = (const char*)Ylds[w];
    #pragma unroll
    for (int es = 0; es < 4; ++es) {
      bf16x8 ya = *(const bf16x8*)(Y + lq * 128 + (((es * 2 + hi) ^ (lq & 7)) << 4));
      #pragma unroll
      for (int ot = 0; ot < 2; ++ot) {
        const float* wp = wg + (size_t)(ot * 32 + lq) * 64 + es * 16 + hi * 8;
        float4 w0 = *(const float4*)wp;
        float4 w1 = *(const float4*)(wp + 4);
        bf16x8 wf;
        wf[0]=(short)f2bf(w0.x); wf[1]=(short)f2bf(w0.y); wf[2]=(short)f2bf(w0.z); wf[3]=(short)f2bf(w0.w);
        wf[4]=(short)f2bf(w1.x); wf[5]=(short)f2bf(w1.y); wf[6]=(short)f2bf(w1.z); wf[7]=(short)f2bf(w1.w);
        if (ot == 0) o0 = __builtin_amdgcn_mfma_f32_32x32x16_bf16(ya, wf, o0, 0, 0, 0);
        else         o1 = __builtin_amdgcn_mfma_f32_32x32x16_bf16(ya, wf, o1, 0, 0, 0);
      }
    }
  }
  const float b0 = bg[lq], b1 = bg[32 + lq];
  float* orow = og + (size_t)bh * HEAD_ELEMS + (size_t)(qblk * 128 + w * 32) * DH;
  #pragma unroll
  for (int r = 0; r < 16; ++r) {
    const int qr_ = (r & 3) + 8 * (r >> 2) + 4 * hi;
    orow[qr_ * 64 + lq]      = o0[r] + b0;
    orow[qr_ * 64 + 32 + lq] = o1[r] + b1;
  }
}

// ================= fallback (verified v1) if ws too small =================
static __device__ __forceinline__ int swz(int row, int col) {
  return row * 128 + ((((col >> 3) ^ (row & 7))) << 4) + ((col & 7) << 1);
}

__global__ __launch_bounds__(256, 2)
void attn_proj_kernel(const float* __restrict__ qg, const float* __restrict__ kg,
                      const float* __restrict__ vg, const float* __restrict__ wg,
                      const float* __restrict__ bg, float* __restrict__ og) {
  __shared__ unsigned short lK[64 * 64];
  __shared__ unsigned short lV[64 * 64];
  __shared__ unsigned short lP[4][16 * 64];

  const int tid  = threadIdx.x;
  const int wave = tid >> 6;
  const int lane = tid & 63;
  const int lg   = lane >> 4;
  const int lr   = lane & 15;
  const int bh = blockIdx.x >> 5;
  const int qt = blockIdx.x & 31;
  const size_t head_off = (size_t)bh * S_LEN * 64;
  const float* qp = qg + head_off;
  const float* kp = kg + head_off;
  const float* vp = vg + head_off;

  const int qrow = qt * 64 + wave * 16 + lr;
  bf16x8 qa[2];
  {
    const float* qr = qp + (size_t)qrow * 64 + lg * 8;
    #pragma unroll
    for (int s = 0; s < 2; ++s) {
      float4 f0 = *(const float4*)(qr + s * 32);
      float4 f1 = *(const float4*)(qr + s * 32 + 4);
      bf16x8 a;
      a[0]=(short)f2bf(f0.x*0.125f); a[1]=(short)f2bf(f0.y*0.125f);
      a[2]=(short)f2bf(f0.z*0.125f); a[3]=(short)f2bf(f0.w*0.125f);
      a[4]=(short)f2bf(f1.x*0.125f); a[5]=(short)f2bf(f1.y*0.125f);
      a[6]=(short)f2bf(f1.z*0.125f); a[7]=(short)f2bf(f1.w*0.125f);
      qa[s] = a;
    }
  }
  f32x4 yacc[4];
  #pragma unroll
  for (int e = 0; e < 4; ++e) yacc[e] = (f32x4){0.f, 0.f, 0.f, 0.f};
  float mrow[4], lrow[4];
  #pragma unroll
  for (int r = 0; r < 4; ++r) { mrow[r] = -INFINITY; lrow[r] = 0.f; }

  for (int kt = 0; kt < S_LEN / 64; ++kt) {
    __syncthreads();
    #pragma unroll
    for (int i = 0; i < 4; ++i) {
      int n = tid + i * 256;
      int row = n >> 4;
      int c4 = (n & 15) * 4;
      const size_t goff = (size_t)(kt * 64 + row) * 64 + c4;
      float4 kf = *(const float4*)(kp + goff);
      unsigned p0 = (unsigned)f2bf(kf.x) | ((unsigned)f2bf(kf.y) << 16);
      unsigned p1 = (unsigned)f2bf(kf.z) | ((unsigned)f2bf(kf.w) << 16);
      uint2 pk2; pk2.x = p0; pk2.y = p1;
      *(uint2*)((char*)lK + swz(row, c4)) = pk2;
      float4 vf = *(const float4*)(vp + goff);
      *(unsigned short*)((char*)lV + swz(c4 + 0, row)) = f2bf(vf.x);
      *(unsigned short*)((char*)lV + swz(c4 + 1, row)) = f2bf(vf.y);
      *(unsigned short*)((char*)lV + swz(c4 + 2, row)) = f2bf(vf.z);
      *(unsigned short*)((char*)lV + swz(c4 + 3, row)) = f2bf(vf.w);
    }
    __syncthreads();
    f32x4 sacc[4];
    #pragma unroll
    for (int c = 0; c < 4; ++c) {
      sacc[c] = (f32x4){0.f, 0.f, 0.f, 0.f};
      #pragma unroll
      for (int s = 0; s < 2; ++s) {
        bf16x8 kb2 = *(const bf16x8*)((const char*)lK + swz(c * 16 + lr, s * 32 + lg * 8));
        sacc[c] = __builtin_amdgcn_mfma_f32_16x16x32_bf16(qa[s], kb2, sacc[c], 0, 0, 0);
      }
    }
    float mt[4], alpha[4];
    #pragma unroll
    for (int r = 0; r < 4; ++r) {
      float mm = fmaxf(fmaxf(sacc[0][r], sacc[1][r]), fmaxf(sacc[2][r], sacc[3][r]));
      mm = fmaxf(mm, __shfl_xor(mm, 1));
      mm = fmaxf(mm, __shfl_xor(mm, 2));
      mm = fmaxf(mm, __shfl_xor(mm, 4));
      mm = fmaxf(mm, __shfl_xor(mm, 8));
      mt[r] = fmaxf(mrow[r], mm);
      alpha[r] = __expf(mrow[r] - mt[r]);
      mrow[r] = mt[r];
    }
    #pragma unroll
    for (int c = 0; c < 4; ++c)
      #pragma unroll
      for (int r = 0; r < 4; ++r) sacc[c][r] = __expf(sacc[c][r] - mt[r]);
    #pragma unroll
    for (int r = 0; r < 4; ++r) {
      float sum = sacc[0][r] + sacc[1][r] + sacc[2][r] + sacc[3][r];
      sum += __shfl_xor(sum, 1);
      sum += __shfl_xor(sum, 2);
      sum += __shfl_xor(sum, 4);
      sum += __shfl_xor(sum, 8);
      lrow[r] = lrow[r] * alpha[r] + sum;
      #pragma unroll
      for (int e = 0; e < 4; ++e) yacc[e][r] *= alpha[r];
    }
    unsigned short* pw = lP[wave];
    #pragma unroll
    for (int c = 0; c < 4; ++c)
      #pragma unroll
      for (int r = 0; r < 4; ++r)
        *(unsigned short*)((char*)pw + swz(lg * 4 + r, c * 16 + lr)) = f2bf(sacc[c][r]);
    asm volatile("s_waitcnt lgkmcnt(0)" ::: "memory");
    #pragma unroll
    for (int s = 0; s < 2; ++s) {
      bf16x8 pa = *(const bf16x8*)((const char*)pw + swz(lr, s * 32 + lg * 8));
      #pragma unroll
      for (int e = 0; e < 4; ++e) {
        bf16x8 vb = *(const bf16x8*)((const char*)lV + swz(e * 16 + lr, s * 32 + lg * 8));
        yacc[e] = __builtin_amdgcn_mfma_f32_16x16x32_bf16(pa, vb, yacc[e], 0, 0, 0);
      }
    }
  }
  unsigned short* pw = lP[wave];
  #pragma unroll
  for (int e = 0; e < 4; ++e)
    #pragma unroll
    for (int r = 0; r < 4; ++r)
      *(unsigned short*)((char*)pw + swz(lg * 4 + r, e * 16 + lr)) = f2bf(yacc[e][r] / lrow[r]);
  asm volatile("s_waitcnt lgkmcnt(0)" ::: "memory");
  f32x4 oacc[4];
  #pragma unroll
  for (int c = 0; c < 4; ++c) oacc[c] = (f32x4){0.f, 0.f, 0.f, 0.f};
  #pragma unroll
  for (int s = 0; s < 2; ++s) {
    bf16x8 ya = *(const bf16x8*)((const char*)pw + swz(lr, s * 32 + lg * 8));
    #pragma unroll
    for (int c = 0; c < 4; ++c) {
      const float* wp = wg + (size_t)(c * 16 + lr) * 64 + s * 32 + lg * 8;
      float4 f0 = *(const float4*)wp;
      float4 f1 = *(const float4*)(wp + 4);
      bf16x8 wb;
      wb[0]=(short)f2bf(f0.x); wb[1]=(short)f2bf(f0.y); wb[2]=(short)f2bf(f0.z); wb[3]=(short)f2bf(f0.w);
      wb[4]=(short)f2bf(f1.x); wb[5]=(short)f2bf(f1.y); wb[6]=(short)f2bf(f1.z); wb[7]=(short)f2bf(f1.w);
      oacc[c] = __builtin_amdgcn_mfma_f32_16x16x32_bf16(ya, wb, oacc[c], 0, 0, 0);
    }
  }
  float* op = og + head_off + (size_t)(qt * 64 + wave * 16) * 64;
  #pragma unroll
  for (int c = 0; c < 4; ++c) {
    float bias = bg[c * 16 + lr];
    #pragma unroll
    for (int r = 0; r < 4; ++r)
      op[(size_t)(lg * 4 + r) * 64 + c * 16 + lr] = oacc[c][r] + bias;
  }
}

extern "C" void kernel_launch(void* const* d_in, const int* in_sizes, int n_in,
                              void* d_out, int out_size, void* d_ws, size_t ws_size,
                              hipStream_t stream) {
  const float* q = (const float*)d_in[0];
  const float* k = (const float*)d_in[1];
  const float* v = (const float*)d_in[2];
  const float* w = (const float*)d_in[3];
  const float* b = (const float*)d_in[4];
  float* out = (float*)d_out;

  const size_t tensor_elems = (size_t)NHEAD * HEAD_ELEMS;           // 8,388,608
  const size_t need = 2ull * tensor_elems * sizeof(unsigned short); // ~33.6 MB

  if (ws_size >= need) {
    unsigned short* kws = (unsigned short*)d_ws;
    unsigned short* vws = kws + tensor_elems;
    prep<<<4096, 256, 0, stream>>>(k, v, kws, vws);
    attn_reg<<<1024, 256, 0, stream>>>(q, kws, vws, w, b, out);
  } else {
    attn_proj_kernel<<<64 * 32, 256, 0, stream>>>(q, k, v, w, b, out);
  }
}

// Round 8
// 230.997 us; speedup vs baseline: 1.0247x; 1.0247x over previous
//
#include <hip/hip_runtime.h>
#include <math.h>

typedef __attribute__((ext_vector_type(8))) short bf16x8;
typedef __attribute__((ext_vector_type(4))) float f32x4;
typedef __attribute__((ext_vector_type(16))) float f32x16;

#define S_LEN 2048
#define DH 64
#define NHEAD 64
#define HEAD_ELEMS (S_LEN * DH)
#define NT (S_LEN / 64)

static __device__ __forceinline__ unsigned short f2bf(float f) {
  union { float f; unsigned u; } v; v.f = f;
  return (unsigned short)((v.u + 0x7fffu + ((v.u >> 16) & 1u)) >> 16);
}

// ---------------- pre-pass: repack K and V into MFMA-fragment-major bf16 ----------------
// (identical to R7-verified version)
__global__ __launch_bounds__(256)
void prep(const float* __restrict__ k, const float* __restrict__ v,
          unsigned short* __restrict__ ko, unsigned short* __restrict__ vt) {
  __shared__ float t[64][65];
  const int tid = threadIdx.x;
  if (blockIdx.x < 2048) {
    const int head = blockIdx.x >> 5;
    const int kt   = blockIdx.x & 31;
    const float* kp = k + (size_t)head * HEAD_ELEMS;
    unsigned short* kout = ko + (size_t)head * HEAD_ELEMS + (size_t)kt * 4096;
    #pragma unroll
    for (int i = 0; i < 2; ++i) {
      const int c     = i * 256 + tid;
      const int chunk = c >> 6;
      const int tt    = chunk >> 2;
      const int d     = chunk & 3;
      const int l     = c & 63;
      const int row   = kt * 64 + tt * 32 + (l & 31);
      const int col   = d * 16 + (l >> 5) * 8;
      const float* src = kp + (size_t)row * DH + col;
      float4 a = *(const float4*)src;
      float4 b = *(const float4*)(src + 4);
      bf16x8 r;
      r[0]=(short)f2bf(a.x); r[1]=(short)f2bf(a.y); r[2]=(short)f2bf(a.z); r[3]=(short)f2bf(a.w);
      r[4]=(short)f2bf(b.x); r[5]=(short)f2bf(b.y); r[6]=(short)f2bf(b.z); r[7]=(short)f2bf(b.w);
      *(bf16x8*)(kout + (size_t)chunk * 512 + l * 8) = r;
    }
  } else {
    const int bi   = blockIdx.x - 2048;
    const int head = bi >> 5;
    const int kc   = bi & 31;
    const float* vp = v + (size_t)head * HEAD_ELEMS + (size_t)kc * 64 * DH;
    #pragma unroll
    for (int i = 0; i < 4; ++i) {
      int fi = tid + i * 256;
      int kk = fi >> 4, e4 = (fi & 15) * 4;
      float4 f = *(const float4*)(vp + kk * DH + e4);
      t[kk][e4] = f.x; t[kk][e4+1] = f.y; t[kk][e4+2] = f.z; t[kk][e4+3] = f.w;
    }
    __syncthreads();
    unsigned short* vout = vt + (size_t)head * HEAD_ELEMS + (size_t)kc * 4096;
    #pragma unroll
    for (int i = 0; i < 2; ++i) {
      const int c     = i * 256 + tid;
      const int chunk = c >> 6;
      const int t2    = chunk >> 2;
      const int kh    = (chunk >> 1) & 1;
      const int eh    = chunk & 1;
      const int l     = c & 63;
      const int e     = eh * 32 + (l & 31);
      const int kr    = t2 * 32 + kh * 16 + (l >> 5) * 8;
      bf16x8 r;
      #pragma unroll
      for (int j = 0; j < 8; ++j) r[j] = (short)f2bf(t[kr + j][e]);
      *(bf16x8*)(vout + (size_t)chunk * 512 + l * 8) = r;
    }
  }
}

// ---------------- main: all-register flash attention, 2-stage register pipeline ----------------
#define LOADKV(KB, VB, it) do {                                              \
    const unsigned short* kp_ = kh_ + (size_t)(it) * 2048;                   \
    const unsigned short* vp_ = vh_ + (size_t)(it) * 2048;                   \
    KB[0] = *(const bf16x8*)(kp_);        KB[1] = *(const bf16x8*)(kp_ + 512);  \
    KB[2] = *(const bf16x8*)(kp_ + 1024); KB[3] = *(const bf16x8*)(kp_ + 1536); \
    VB[0] = *(const bf16x8*)(vp_);        VB[1] = *(const bf16x8*)(vp_ + 512);  \
    VB[2] = *(const bf16x8*)(vp_ + 1024); VB[3] = *(const bf16x8*)(vp_ + 1536); \
  } while (0)

#define COMPUTE(KB, VB) do {                                                 \
    f32x16 s;                                                                \
    __builtin_amdgcn_s_setprio(1);                                           \
    s = __builtin_amdgcn_mfma_f32_32x32x16_bf16(KB[0], qf[0], zv, 0, 0, 0);  \
    s = __builtin_amdgcn_mfma_f32_32x32x16_bf16(KB[1], qf[1], s, 0, 0, 0);   \
    s = __builtin_amdgcn_mfma_f32_32x32x16_bf16(KB[2], qf[2], s, 0, 0, 0);   \
    s = __builtin_amdgcn_mfma_f32_32x32x16_bf16(KB[3], qf[3], s, 0, 0, 0);   \
    __builtin_amdgcn_s_setprio(0);                                           \
    unsigned pk[8];                                                          \
    _Pragma("unroll")                                                        \
    for (int i_ = 0; i_ < 8; ++i_) {                                         \
      float ea = exp2f(s[2 * i_]);                                           \
      float eb = exp2f(s[2 * i_ + 1]);                                       \
      if (i_ & 1) ls1 += ea + eb; else ls0 += ea + eb;                       \
      asm("v_cvt_pk_bf16_f32 %0, %1, %2" : "=v"(pk[i_]) : "v"(ea), "v"(eb)); \
    }                                                                        \
    asm volatile("v_permlane32_swap_b32 %0, %1" : "+v"(pk[0]), "+v"(pk[2])); \
    asm volatile("v_permlane32_swap_b32 %0, %1" : "+v"(pk[1]), "+v"(pk[3])); \
    asm volatile("v_permlane32_swap_b32 %0, %1" : "+v"(pk[4]), "+v"(pk[6])); \
    asm volatile("v_permlane32_swap_b32 %0, %1" : "+v"(pk[5]), "+v"(pk[7])); \
    union { unsigned u[4]; bf16x8 v; } pf0, pf1;                             \
    pf0.u[0] = pk[0]; pf0.u[1] = pk[1]; pf0.u[2] = pk[2]; pf0.u[3] = pk[3];  \
    pf1.u[0] = pk[4]; pf1.u[1] = pk[5]; pf1.u[2] = pk[6]; pf1.u[3] = pk[7];  \
    __builtin_amdgcn_s_setprio(1);                                           \
    yacc0 = __builtin_amdgcn_mfma_f32_32x32x16_bf16(pf0.v, VB[0], yacc0, 0, 0, 0); \
    yacc0 = __builtin_amdgcn_mfma_f32_32x32x16_bf16(pf1.v, VB[2], yacc0, 0, 0, 0); \
    yacc1 = __builtin_amdgcn_mfma_f32_32x32x16_bf16(pf0.v, VB[1], yacc1, 0, 0, 0); \
    yacc1 = __builtin_amdgcn_mfma_f32_32x32x16_bf16(pf1.v, VB[3], yacc1, 0, 0, 0); \
    __builtin_amdgcn_s_setprio(0);                                           \
  } while (0)

__global__ __launch_bounds__(256, 3)
void attn_reg(const float* __restrict__ qg, const unsigned short* __restrict__ kfb,
              const unsigned short* __restrict__ vfb, const float* __restrict__ wg,
              const float* __restrict__ bg, float* __restrict__ og) {
  __shared__ __align__(16) unsigned short Ylds[4][2048];  // epilogue only
  __shared__ float stats[4][32];

  const int tid = threadIdx.x;
  const int w   = tid >> 6;     // 0..3
  const int l   = tid & 63;
  const int lq  = l & 31;
  const int hi  = l >> 5;

  // XCD swizzle (1024 wgs, 8 XCDs)
  const int bxs  = ((blockIdx.x & 7) << 7) | (blockIdx.x >> 3);
  const int bh   = bxs >> 4;
  const int qblk = bxs & 15;

  const unsigned short* kh_ = kfb + (size_t)bh * HEAD_ELEMS + l * 8;
  const unsigned short* vh_ = vfb + (size_t)bh * HEAD_ELEMS + l * 8;

  // Q B-fragments from f32 global; 1/sqrt(64)*log2(e) folded in
  bf16x8 qf[4];
  {
    const float QS = 0.125f * 1.44269504f;
    const float* qfp = qg + (size_t)bh * HEAD_ELEMS
                     + (size_t)(qblk * 128 + w * 32 + lq) * DH + hi * 8;
    #pragma unroll
    for (int d = 0; d < 4; ++d) {
      float4 f0 = *(const float4*)(qfp + d * 16);
      float4 f1 = *(const float4*)(qfp + d * 16 + 4);
      bf16x8 a;
      a[0]=(short)f2bf(f0.x*QS); a[1]=(short)f2bf(f0.y*QS);
      a[2]=(short)f2bf(f0.z*QS); a[3]=(short)f2bf(f0.w*QS);
      a[4]=(short)f2bf(f1.x*QS); a[5]=(short)f2bf(f1.y*QS);
      a[6]=(short)f2bf(f1.z*QS); a[7]=(short)f2bf(f1.w*QS);
      qf[d] = a;
    }
  }

  f32x16 yacc0, yacc1, zv;
  #pragma unroll
  for (int i = 0; i < 16; ++i) { yacc0[i] = 0.f; yacc1[i] = 0.f; zv[i] = 0.f; }
  float ls0 = 0.f, ls1 = 0.f;

  // ---- 2-stage register pipeline: LOAD(next) issued before COMPUTE(cur) ----
  bf16x8 kA[4], vA[4], kB[4], vB[4];
  LOADKV(kA, vA, 0);
  for (int it = 0; it < 2 * NT; it += 2) {
    LOADKV(kB, vB, it + 1);          // in flight across COMPUTE(A)
    COMPUTE(kA, vA);
    if (it + 2 < 2 * NT) LOADKV(kA, vA, it + 2);   // in flight across COMPUTE(B)
    COMPUTE(kB, vB);
  }
  float lsum = ls0 + ls1;

  // ---- lsum: col domain -> row domain via per-wave stats LDS (R3-verified) ----
  lsum += __shfl_xor(lsum, 32);
  if (hi == 0) stats[w][lq] = 1.0f / lsum;
  asm volatile("s_waitcnt lgkmcnt(0)" ::: "memory");
  __builtin_amdgcn_sched_barrier(0);

  // ---- epilogue: normalize (row-domain stats), Y -> LDS, project, bias, store ----
  {
    char* Y = (char*)Ylds[w];
    #pragma unroll
    for (int et = 0; et < 2; ++et) {
      f32x16& ya = et ? yacc1 : yacc0;
      const int e = et * 32 + lq;
      #pragma unroll
      for (int r = 0; r < 16; ++r) {
        const int qr_ = (r & 3) + 8 * (r >> 2) + 4 * hi;
        *(unsigned short*)(Y + qr_ * 128 + (((e >> 3) ^ (qr_ & 7)) << 4) + (e & 7) * 2)
            = f2bf(ya[r] * stats[w][qr_]);
      }
    }
  }
  asm volatile("s_waitcnt lgkmcnt(0)" ::: "memory");
  __builtin_amdgcn_sched_barrier(0);

  f32x16 o0, o1;
  #pragma unroll
  for (int i = 0; i < 16; ++i) { o0[i] = 0.f; o1[i] = 0.f; }
  {
    const char* Y = (const char*)Ylds[w];
    #pragma unroll
    for (int es = 0; es < 4; ++es) {
      bf16x8 ya = *(const bf16x8*)(Y + lq * 128 + (((es * 2 + hi) ^ (lq & 7)) << 4));
      #pragma unroll
      for (int ot = 0; ot < 2; ++ot) {
        const float* wp = wg + (size_t)(ot * 32 + lq) * 64 + es * 16 + hi * 8;
        float4 w0 = *(const float4*)wp;
        float4 w1 = *(const float4*)(wp + 4);
        bf16x8 wf;
        wf[0]=(short)f2bf(w0.x); wf[1]=(short)f2bf(w0.y); wf[2]=(short)f2bf(w0.z); wf[3]=(short)f2bf(w0.w);
        wf[4]=(short)f2bf(w1.x); wf[5]=(short)f2bf(w1.y); wf[6]=(short)f2bf(w1.z); wf[7]=(short)f2bf(w1.w);
        if (ot == 0) o0 = __builtin_amdgcn_mfma_f32_32x32x16_bf16(ya, wf, o0, 0, 0, 0);
        else         o1 = __builtin_amdgcn_mfma_f32_32x32x16_bf16(ya, wf, o1, 0, 0, 0);
      }
    }
  }
  const float b0 = bg[lq], b1 = bg[32 + lq];
  float* orow = og + (size_t)bh * HEAD_ELEMS + (size_t)(qblk * 128 + w * 32) * DH;
  #pragma unroll
  for (int r = 0; r < 16; ++r) {
    const int qr_ = (r & 3) + 8 * (r >> 2) + 4 * hi;
    orow[qr_ * 64 + lq]      = o0[r] + b0;
    orow[qr_ * 64 + 32 + lq] = o1[r] + b1;
  }
}

// ================= fallback (verified v1) if ws too small =================
static __device__ __forceinline__ int swz(int row, int col) {
  return row * 128 + ((((col >> 3) ^ (row & 7))) << 4) + ((col & 7) << 1);
}

__global__ __launch_bounds__(256, 2)
void attn_proj_kernel(const float* __restrict__ qg, const float* __restrict__ kg,
                      const float* __restrict__ vg, const float* __restrict__ wg,
                      const float* __restrict__ bg, float* __restrict__ og) {
  __shared__ unsigned short lK[64 * 64];
  __shared__ unsigned short lV[64 * 64];
  __shared__ unsigned short lP[4][16 * 64];

  const int tid  = threadIdx.x;
  const int wave = tid >> 6;
  const int lane = tid & 63;
  const int lg   = lane >> 4;
  const int lr   = lane & 15;
  const int bh = blockIdx.x >> 5;
  const int qt = blockIdx.x & 31;
  const size_t head_off = (size_t)bh * S_LEN * 64;
  const float* qp = qg + head_off;
  const float* kp = kg + head_off;
  const float* vp = vg + head_off;

  const int qrow = qt * 64 + wave * 16 + lr;
  bf16x8 qa[2];
  {
    const float* qr = qp + (size_t)qrow * 64 + lg * 8;
    #pragma unroll
    for (int s = 0; s < 2; ++s) {
      float4 f0 = *(const float4*)(qr + s * 32);
      float4 f1 = *(const float4*)(qr + s * 32 + 4);
      bf16x8 a;
      a[0]=(short)f2bf(f0.x*0.125f); a[1]=(short)f2bf(f0.y*0.125f);
      a[2]=(short)f2bf(f0.z*0.125f); a[3]=(short)f2bf(f0.w*0.125f);
      a[4]=(short)f2bf(f1.x*0.125f); a[5]=(short)f2bf(f1.y*0.125f);
      a[6]=(short)f2bf(f1.z*0.125f); a[7]=(short)f2bf(f1.w*0.125f);
      qa[s] = a;
    }
  }
  f32x4 yacc[4];
  #pragma unroll
  for (int e = 0; e < 4; ++e) yacc[e] = (f32x4){0.f, 0.f, 0.f, 0.f};
  float mrow[4], lrow[4];
  #pragma unroll
  for (int r = 0; r < 4; ++r) { mrow[r] = -INFINITY; lrow[r] = 0.f; }

  for (int kt = 0; kt < S_LEN / 64; ++kt) {
    __syncthreads();
    #pragma unroll
    for (int i = 0; i < 4; ++i) {
      int n = tid + i * 256;
      int row = n >> 4;
      int c4 = (n & 15) * 4;
      const size_t goff = (size_t)(kt * 64 + row) * 64 + c4;
      float4 kf = *(const float4*)(kp + goff);
      unsigned p0 = (unsigned)f2bf(kf.x) | ((unsigned)f2bf(kf.y) << 16);
      unsigned p1 = (unsigned)f2bf(kf.z) | ((unsigned)f2bf(kf.w) << 16);
      uint2 pk2; pk2.x = p0; pk2.y = p1;
      *(uint2*)((char*)lK + swz(row, c4)) = pk2;
      float4 vf = *(const float4*)(vp + goff);
      *(unsigned short*)((char*)lV + swz(c4 + 0, row)) = f2bf(vf.x);
      *(unsigned short*)((char*)lV + swz(c4 + 1, row)) = f2bf(vf.y);
      *(unsigned short*)((char*)lV + swz(c4 + 2, row)) = f2bf(vf.z);
      *(unsigned short*)((char*)lV + swz(c4 + 3, row)) = f2bf(vf.w);
    }
    __syncthreads();
    f32x4 sacc[4];
    #pragma unroll
    for (int c = 0; c < 4; ++c) {
      sacc[c] = (f32x4){0.f, 0.f, 0.f, 0.f};
      #pragma unroll
      for (int s = 0; s < 2; ++s) {
        bf16x8 kb2 = *(const bf16x8*)((const char*)lK + swz(c * 16 + lr, s * 32 + lg * 8));
        sacc[c] = __builtin_amdgcn_mfma_f32_16x16x32_bf16(qa[s], kb2, sacc[c], 0, 0, 0);
      }
    }
    float mt[4], alpha[4];
    #pragma unroll
    for (int r = 0; r < 4; ++r) {
      float mm = fmaxf(fmaxf(sacc[0][r], sacc[1][r]), fmaxf(sacc[2][r], sacc[3][r]));
      mm = fmaxf(mm, __shfl_xor(mm, 1));
      mm = fmaxf(mm, __shfl_xor(mm, 2));
      mm = fmaxf(mm, __shfl_xor(mm, 4));
      mm = fmaxf(mm, __shfl_xor(mm, 8));
      mt[r] = fmaxf(mrow[r], mm);
      alpha[r] = __expf(mrow[r] - mt[r]);
      mrow[r] = mt[r];
    }
    #pragma unroll
    for (int c = 0; c < 4; ++c)
      #pragma unroll
      for (int r = 0; r < 4; ++r) sacc[c][r] = __expf(sacc[c][r] - mt[r]);
    #pragma unroll
    for (int r = 0; r < 4; ++r) {
      float sum = sacc[0][r] + sacc[1][r] + sacc[2][r] + sacc[3][r];
      sum += __shfl_xor(sum, 1);
      sum += __shfl_xor(sum, 2);
      sum += __shfl_xor(sum, 4);
      sum += __shfl_xor(sum, 8);
      lrow[r] = lrow[r] * alpha[r] + sum;
      #pragma unroll
      for (int e = 0; e < 4; ++e) yacc[e][r] *= alpha[r];
    }
    unsigned short* pw = lP[wave];
    #pragma unroll
    for (int c = 0; c < 4; ++c)
      #pragma unroll
      for (int r = 0; r < 4; ++r)
        *(unsigned short*)((char*)pw + swz(lg * 4 + r, c * 16 + lr)) = f2bf(sacc[c][r]);
    asm volatile("s_waitcnt lgkmcnt(0)" ::: "memory");
    #pragma unroll
    for (int s = 0; s < 2; ++s) {
      bf16x8 pa = *(const bf16x8*)((const char*)pw + swz(lr, s * 32 + lg * 8));
      #pragma unroll
      for (int e = 0; e < 4; ++e) {
        bf16x8 vb = *(const bf16x8*)((const char*)lV + swz(e * 16 + lr, s * 32 + lg * 8));
        yacc[e] = __builtin_amdgcn_mfma_f32_16x16x32_bf16(pa, vb, yacc[e], 0, 0, 0);
      }
    }
  }
  unsigned short* pw = lP[wave];
  #pragma unroll
  for (int e = 0; e < 4; ++e)
    #pragma unroll
    for (int r = 0; r < 4; ++r)
      *(unsigned short*)((char*)pw + swz(lg * 4 + r, e * 16 + lr)) = f2bf(yacc[e][r] / lrow[r]);
  asm volatile("s_waitcnt lgkmcnt(0)" ::: "memory");
  f32x4 oacc[4];
  #pragma unroll
  for (int c = 0; c < 4; ++c) oacc[c] = (f32x4){0.f, 0.f, 0.f, 0.f};
  #pragma unroll
  for (int s = 0; s < 2; ++s) {
    bf16x8 ya = *(const bf16x8*)((const char*)pw + swz(lr, s * 32 + lg * 8));
    #pragma unroll
    for (int c = 0; c < 4; ++c) {
      const float* wp = wg + (size_t)(c * 16 + lr) * 64 + s * 32 + lg * 8;
      float4 f0 = *(const float4*)wp;
      float4 f1 = *(const float4*)(wp + 4);
      bf16x8 wb;
      wb[0]=(short)f2bf(f0.x); wb[1]=(short)f2bf(f0.y); wb[2]=(short)f2bf(f0.z); wb[3]=(short)f2bf(f0.w);
      wb[4]=(short)f2bf(f1.x); wb[5]=(short)f2bf(f1.y); wb[6]=(short)f2bf(f1.z); wb[7]=(short)f2bf(f1.w);
      oacc[c] = __builtin_amdgcn_mfma_f32_16x16x32_bf16(ya, wb, oacc[c], 0, 0, 0);
    }
  }
  float* op = og + head_off + (size_t)(qt * 64 + wave * 16) * 64;
  #pragma unroll
  for (int c = 0; c < 4; ++c) {
    float bias = bg[c * 16 + lr];
    #pragma unroll
    for (int r = 0; r < 4; ++r)
      op[(size_t)(lg * 4 + r) * 64 + c * 16 + lr] = oacc[c][r] + bias;
  }
}

extern "C" void kernel_launch(void* const* d_in, const int* in_sizes, int n_in,
                              void* d_out, int out_size, void* d_ws, size_t ws_size,
                              hipStream_t stream) {
  const float* q = (const float*)d_in[0];
  const float* k = (const float*)d_in[1];
  const float* v = (const float*)d_in[2];
  const float* w = (const float*)d_in[3];
  const float* b = (const float*)d_in[4];
  float* out = (float*)d_out;

  const size_t tensor_elems = (size_t)NHEAD * HEAD_ELEMS;           // 8,388,608
  const size_t need = 2ull * tensor_elems * sizeof(unsigned short); // ~33.6 MB

  if (ws_size >= need) {
    unsigned short* kws = (unsigned short*)d_ws;
    unsigned short* vws = kws + tensor_elems;
    prep<<<4096, 256, 0, stream>>>(k, v, kws, vws);
    attn_reg<<<1024, 256, 0, stream>>>(q, kws, vws, w, b, out);
  } else {
    attn_proj_kernel<<<64 * 32, 256, 0, stream>>>(q, k, v, w, b, out);
  }
}

// Round 9
// 229.584 us; speedup vs baseline: 1.0310x; 1.0062x over previous
//
#include <hip/hip_runtime.h>
#include <math.h>

typedef __attribute__((ext_vector_type(8))) short bf16x8;
typedef __attribute__((ext_vector_type(4))) float f32x4;
typedef __attribute__((ext_vector_type(16))) float f32x16;

#define S_LEN 2048
#define DH 64
#define NHEAD 64
#define HEAD_ELEMS (S_LEN * DH)
#define NT (S_LEN / 64)

static __device__ __forceinline__ unsigned short f2bf(float f) {
  union { float f; unsigned u; } v; v.f = f;
  return (unsigned short)((v.u + 0x7fffu + ((v.u >> 16) & 1u)) >> 16);
}

// ---------------- pre-pass: repack K and V into MFMA-fragment-major bf16 ----------------
// (identical to R7-verified version)
__global__ __launch_bounds__(256)
void prep(const float* __restrict__ k, const float* __restrict__ v,
          unsigned short* __restrict__ ko, unsigned short* __restrict__ vt) {
  __shared__ float t[64][65];
  const int tid = threadIdx.x;
  if (blockIdx.x < 2048) {
    const int head = blockIdx.x >> 5;
    const int kt   = blockIdx.x & 31;
    const float* kp = k + (size_t)head * HEAD_ELEMS;
    unsigned short* kout = ko + (size_t)head * HEAD_ELEMS + (size_t)kt * 4096;
    #pragma unroll
    for (int i = 0; i < 2; ++i) {
      const int c     = i * 256 + tid;
      const int chunk = c >> 6;
      const int tt    = chunk >> 2;
      const int d     = chunk & 3;
      const int l     = c & 63;
      const int row   = kt * 64 + tt * 32 + (l & 31);
      const int col   = d * 16 + (l >> 5) * 8;
      const float* src = kp + (size_t)row * DH + col;
      float4 a = *(const float4*)src;
      float4 b = *(const float4*)(src + 4);
      bf16x8 r;
      r[0]=(short)f2bf(a.x); r[1]=(short)f2bf(a.y); r[2]=(short)f2bf(a.z); r[3]=(short)f2bf(a.w);
      r[4]=(short)f2bf(b.x); r[5]=(short)f2bf(b.y); r[6]=(short)f2bf(b.z); r[7]=(short)f2bf(b.w);
      *(bf16x8*)(kout + (size_t)chunk * 512 + l * 8) = r;
    }
  } else {
    const int bi   = blockIdx.x - 2048;
    const int head = bi >> 5;
    const int kc   = bi & 31;
    const float* vp = v + (size_t)head * HEAD_ELEMS + (size_t)kc * 64 * DH;
    #pragma unroll
    for (int i = 0; i < 4; ++i) {
      int fi = tid + i * 256;
      int kk = fi >> 4, e4 = (fi & 15) * 4;
      float4 f = *(const float4*)(vp + kk * DH + e4);
      t[kk][e4] = f.x; t[kk][e4+1] = f.y; t[kk][e4+2] = f.z; t[kk][e4+3] = f.w;
    }
    __syncthreads();
    unsigned short* vout = vt + (size_t)head * HEAD_ELEMS + (size_t)kc * 4096;
    #pragma unroll
    for (int i = 0; i < 2; ++i) {
      const int c     = i * 256 + tid;
      const int chunk = c >> 6;
      const int t2    = chunk >> 2;
      const int kh    = (chunk >> 1) & 1;
      const int eh    = chunk & 1;
      const int l     = c & 63;
      const int e     = eh * 32 + (l & 31);
      const int kr    = t2 * 32 + kh * 16 + (l >> 5) * 8;
      bf16x8 r;
      #pragma unroll
      for (int j = 0; j < 8; ++j) r[j] = (short)f2bf(t[kr + j][e]);
      *(bf16x8*)(vout + (size_t)chunk * 512 + l * 8) = r;
    }
  }
}

// softmax+pack+PV for one q-tile (col-domain lsum LS; accumulators Y0/Y1)
#define SOFTMAX_PV(S, LS, Y0, Y1) do {                                        \
    unsigned pk[8];                                                           \
    _Pragma("unroll")                                                         \
    for (int i_ = 0; i_ < 8; ++i_) {                                          \
      float ea = exp2f(S[2 * i_]);                                            \
      float eb = exp2f(S[2 * i_ + 1]);                                        \
      LS += ea + eb;                                                          \
      asm("v_cvt_pk_bf16_f32 %0, %1, %2" : "=v"(pk[i_]) : "v"(ea), "v"(eb));  \
    }                                                                         \
    asm volatile("v_permlane32_swap_b32 %0, %1" : "+v"(pk[0]), "+v"(pk[2]));  \
    asm volatile("v_permlane32_swap_b32 %0, %1" : "+v"(pk[1]), "+v"(pk[3]));  \
    asm volatile("v_permlane32_swap_b32 %0, %1" : "+v"(pk[4]), "+v"(pk[6]));  \
    asm volatile("v_permlane32_swap_b32 %0, %1" : "+v"(pk[5]), "+v"(pk[7]));  \
    union { unsigned u[4]; bf16x8 v; } pf0, pf1;                              \
    pf0.u[0] = pk[0]; pf0.u[1] = pk[1]; pf0.u[2] = pk[2]; pf0.u[3] = pk[3];   \
    pf1.u[0] = pk[4]; pf1.u[1] = pk[5]; pf1.u[2] = pk[6]; pf1.u[3] = pk[7];   \
    __builtin_amdgcn_s_setprio(1);                                            \
    Y0 = __builtin_amdgcn_mfma_f32_32x32x16_bf16(pf0.v, vf[0], Y0, 0, 0, 0);  \
    Y0 = __builtin_amdgcn_mfma_f32_32x32x16_bf16(pf1.v, vf[2], Y0, 0, 0, 0);  \
    Y1 = __builtin_amdgcn_mfma_f32_32x32x16_bf16(pf0.v, vf[1], Y1, 0, 0, 0);  \
    Y1 = __builtin_amdgcn_mfma_f32_32x32x16_bf16(pf1.v, vf[3], Y1, 0, 0, 0);  \
    __builtin_amdgcn_s_setprio(0);                                            \
  } while (0)

// epilogue for one q-tile: normalize (row-domain), LDS layout fix, project, store
#define EPILOGUE(Y0, Y1, T2) do {                                             \
    char* Y = (char*)Ylds[w];                                                 \
    _Pragma("unroll")                                                         \
    for (int et = 0; et < 2; ++et) {                                          \
      f32x16& ya = et ? Y1 : Y0;                                              \
      const int e = et * 32 + lq;                                             \
      _Pragma("unroll")                                                       \
      for (int r = 0; r < 16; ++r) {                                          \
        const int qr_ = (r & 3) + 8 * (r >> 2) + 4 * hi;                      \
        *(unsigned short*)(Y + qr_ * 128 + (((e >> 3) ^ (qr_ & 7)) << 4) + (e & 7) * 2) \
            = f2bf(ya[r] * stats[w][(T2) * 32 + qr_]);                        \
      }                                                                       \
    }                                                                         \
    asm volatile("s_waitcnt lgkmcnt(0)" ::: "memory");                        \
    __builtin_amdgcn_sched_barrier(0);                                        \
    f32x16 o0, o1;                                                            \
    _Pragma("unroll")                                                         \
    for (int i = 0; i < 16; ++i) { o0[i] = 0.f; o1[i] = 0.f; }                \
    _Pragma("unroll")                                                         \
    for (int es = 0; es < 4; ++es) {                                          \
      bf16x8 ya = *(const bf16x8*)((const char*)Ylds[w] + lq * 128 + (((es * 2 + hi) ^ (lq & 7)) << 4)); \
      _Pragma("unroll")                                                       \
      for (int ot = 0; ot < 2; ++ot) {                                        \
        const float* wp = wg + (size_t)(ot * 32 + lq) * 64 + es * 16 + hi * 8; \
        float4 w0 = *(const float4*)wp;                                       \
        float4 w1 = *(const float4*)(wp + 4);                                 \
        bf16x8 wf;                                                            \
        wf[0]=(short)f2bf(w0.x); wf[1]=(short)f2bf(w0.y); wf[2]=(short)f2bf(w0.z); wf[3]=(short)f2bf(w0.w); \
        wf[4]=(short)f2bf(w1.x); wf[5]=(short)f2bf(w1.y); wf[6]=(short)f2bf(w1.z); wf[7]=(short)f2bf(w1.w); \
        if (ot == 0) o0 = __builtin_amdgcn_mfma_f32_32x32x16_bf16(ya, wf, o0, 0, 0, 0); \
        else         o1 = __builtin_amdgcn_mfma_f32_32x32x16_bf16(ya, wf, o1, 0, 0, 0); \
      }                                                                       \
    }                                                                         \
    const float b0 = bg[lq], b1 = bg[32 + lq];                                \
    float* orow = og + (size_t)bh * HEAD_ELEMS                                \
                + (size_t)(qblk * 256 + (T2) * 128 + w * 32) * DH;            \
    _Pragma("unroll")                                                         \
    for (int r = 0; r < 16; ++r) {                                            \
      const int qr_ = (r & 3) + 8 * (r >> 2) + 4 * hi;                        \
      orow[qr_ * 64 + lq]      = o0[r] + b0;                                  \
      orow[qr_ * 64 + 32 + lq] = o1[r] + b1;                                  \
    }                                                                         \
    asm volatile("s_waitcnt lgkmcnt(0)" ::: "memory");                        \
    __builtin_amdgcn_sched_barrier(0);                                        \
  } while (0)

// ---------------- main: all-register flash attention, 2 q-tiles per wave ----------------
__global__ __launch_bounds__(256, 2)
void attn_reg2(const float* __restrict__ qg, const unsigned short* __restrict__ kfb,
               const unsigned short* __restrict__ vfb, const float* __restrict__ wg,
               const float* __restrict__ bg, float* __restrict__ og) {
  __shared__ __align__(16) unsigned short Ylds[4][2048];  // epilogue only
  __shared__ float stats[4][64];

  const int tid = threadIdx.x;
  const int w   = tid >> 6;     // 0..3
  const int l   = tid & 63;
  const int lq  = l & 31;
  const int hi  = l >> 5;

  // XCD swizzle (512 wgs, 8 XCDs): heads x*8..x*8+7 per XCD (KV = 4MB = L2)
  const int bxs  = ((blockIdx.x & 7) << 6) | (blockIdx.x >> 3);
  const int bh   = bxs >> 3;
  const int qblk = bxs & 7;

  const unsigned short* kh_ = kfb + (size_t)bh * HEAD_ELEMS + l * 8;
  const unsigned short* vh_ = vfb + (size_t)bh * HEAD_ELEMS + l * 8;

  // Q B-fragments for TWO q-tiles; 1/sqrt(64)*log2(e) folded in
  bf16x8 qa[4], qb[4];
  {
    const float QS = 0.125f * 1.44269504f;
    #pragma unroll
    for (int t2 = 0; t2 < 2; ++t2) {
      const float* qfp = qg + (size_t)bh * HEAD_ELEMS
                       + (size_t)(qblk * 256 + t2 * 128 + w * 32 + lq) * DH + hi * 8;
      #pragma unroll
      for (int d = 0; d < 4; ++d) {
        float4 f0 = *(const float4*)(qfp + d * 16);
        float4 f1 = *(const float4*)(qfp + d * 16 + 4);
        bf16x8 a;
        a[0]=(short)f2bf(f0.x*QS); a[1]=(short)f2bf(f0.y*QS);
        a[2]=(short)f2bf(f0.z*QS); a[3]=(short)f2bf(f0.w*QS);
        a[4]=(short)f2bf(f1.x*QS); a[5]=(short)f2bf(f1.y*QS);
        a[6]=(short)f2bf(f1.z*QS); a[7]=(short)f2bf(f1.w*QS);
        if (t2 == 0) qa[d] = a; else qb[d] = a;
      }
    }
  }

  f32x16 ya0, ya1, yb0, yb1, zv;
  #pragma unroll
  for (int i = 0; i < 16; ++i) { ya0[i]=0.f; ya1[i]=0.f; yb0[i]=0.f; yb1[i]=0.f; zv[i]=0.f; }
  float lsA = 0.f, lsB = 0.f;

  for (int it = 0; it < 2 * NT; ++it) {   // 64 fragment-sets of 32 k-rows
    const unsigned short* kp_ = kh_ + (size_t)it * 2048;
    const unsigned short* vp_ = vh_ + (size_t)it * 2048;
    bf16x8 kf[4], vf[4];
    kf[0] = *(const bf16x8*)(kp_);        kf[1] = *(const bf16x8*)(kp_ + 512);
    kf[2] = *(const bf16x8*)(kp_ + 1024); kf[3] = *(const bf16x8*)(kp_ + 1536);
    vf[0] = *(const bf16x8*)(vp_);        vf[1] = *(const bf16x8*)(vp_ + 512);
    vf[2] = *(const bf16x8*)(vp_ + 1024); vf[3] = *(const bf16x8*)(vp_ + 1536);

    // two INDEPENDENT QK chains (better MFMA pipe overlap)
    f32x16 sA, sB;
    __builtin_amdgcn_s_setprio(1);
    sA = __builtin_amdgcn_mfma_f32_32x32x16_bf16(kf[0], qa[0], zv, 0, 0, 0);
    sB = __builtin_amdgcn_mfma_f32_32x32x16_bf16(kf[0], qb[0], zv, 0, 0, 0);
    sA = __builtin_amdgcn_mfma_f32_32x32x16_bf16(kf[1], qa[1], sA, 0, 0, 0);
    sB = __builtin_amdgcn_mfma_f32_32x32x16_bf16(kf[1], qb[1], sB, 0, 0, 0);
    sA = __builtin_amdgcn_mfma_f32_32x32x16_bf16(kf[2], qa[2], sA, 0, 0, 0);
    sB = __builtin_amdgcn_mfma_f32_32x32x16_bf16(kf[2], qb[2], sB, 0, 0, 0);
    sA = __builtin_amdgcn_mfma_f32_32x32x16_bf16(kf[3], qa[3], sA, 0, 0, 0);
    sB = __builtin_amdgcn_mfma_f32_32x32x16_bf16(kf[3], qb[3], sB, 0, 0, 0);
    __builtin_amdgcn_s_setprio(0);

    SOFTMAX_PV(sA, lsA, ya0, ya1);
    SOFTMAX_PV(sB, lsB, yb0, yb1);
  }

  // ---- lsum: col domain -> row domain via per-wave stats LDS ----
  lsA += __shfl_xor(lsA, 32);
  lsB += __shfl_xor(lsB, 32);
  if (hi == 0) { stats[w][lq] = 1.0f / lsA; stats[w][32 + lq] = 1.0f / lsB; }
  asm volatile("s_waitcnt lgkmcnt(0)" ::: "memory");
  __builtin_amdgcn_sched_barrier(0);

  EPILOGUE(ya0, ya1, 0);
  EPILOGUE(yb0, yb1, 1);
}

// ================= fallback (verified v1) if ws too small =================
static __device__ __forceinline__ int swz(int row, int col) {
  return row * 128 + ((((col >> 3) ^ (row & 7))) << 4) + ((col & 7) << 1);
}

__global__ __launch_bounds__(256, 2)
void attn_proj_kernel(const float* __restrict__ qg, const float* __restrict__ kg,
                      const float* __restrict__ vg, const float* __restrict__ wg,
                      const float* __restrict__ bg, float* __restrict__ og) {
  __shared__ unsigned short lK[64 * 64];
  __shared__ unsigned short lV[64 * 64];
  __shared__ unsigned short lP[4][16 * 64];

  const int tid  = threadIdx.x;
  const int wave = tid >> 6;
  const int lane = tid & 63;
  const int lg   = lane >> 4;
  const int lr   = lane & 15;
  const int bh = blockIdx.x >> 5;
  const int qt = blockIdx.x & 31;
  const size_t head_off = (size_t)bh * S_LEN * 64;
  const float* qp = qg + head_off;
  const float* kp = kg + head_off;
  const float* vp = vg + head_off;

  const int qrow = qt * 64 + wave * 16 + lr;
  bf16x8 qa[2];
  {
    const float* qr = qp + (size_t)qrow * 64 + lg * 8;
    #pragma unroll
    for (int s = 0; s < 2; ++s) {
      float4 f0 = *(const float4*)(qr + s * 32);
      float4 f1 = *(const float4*)(qr + s * 32 + 4);
      bf16x8 a;
      a[0]=(short)f2bf(f0.x*0.125f); a[1]=(short)f2bf(f0.y*0.125f);
      a[2]=(short)f2bf(f0.z*0.125f); a[3]=(short)f2bf(f0.w*0.125f);
      a[4]=(short)f2bf(f1.x*0.125f); a[5]=(short)f2bf(f1.y*0.125f);
      a[6]=(short)f2bf(f1.z*0.125f); a[7]=(short)f2bf(f1.w*0.125f);
      qa[s] = a;
    }
  }
  f32x4 yacc[4];
  #pragma unroll
  for (int e = 0; e < 4; ++e) yacc[e] = (f32x4){0.f, 0.f, 0.f, 0.f};
  float mrow[4], lrow[4];
  #pragma unroll
  for (int r = 0; r < 4; ++r) { mrow[r] = -INFINITY; lrow[r] = 0.f; }

  for (int kt = 0; kt < S_LEN / 64; ++kt) {
    __syncthreads();
    #pragma unroll
    for (int i = 0; i < 4; ++i) {
      int n = tid + i * 256;
      int row = n >> 4;
      int c4 = (n & 15) * 4;
      const size_t goff = (size_t)(kt * 64 + row) * 64 + c4;
      float4 kf = *(const float4*)(kp + goff);
      unsigned p0 = (unsigned)f2bf(kf.x) | ((unsigned)f2bf(kf.y) << 16);
      unsigned p1 = (unsigned)f2bf(kf.z) | ((unsigned)f2bf(kf.w) << 16);
      uint2 pk2; pk2.x = p0; pk2.y = p1;
      *(uint2*)((char*)lK + swz(row, c4)) = pk2;
      float4 vf = *(const float4*)(vp + goff);
      *(unsigned short*)((char*)lV + swz(c4 + 0, row)) = f2bf(vf.x);
      *(unsigned short*)((char*)lV + swz(c4 + 1, row)) = f2bf(vf.y);
      *(unsigned short*)((char*)lV + swz(c4 + 2, row)) = f2bf(vf.z);
      *(unsigned short*)((char*)lV + swz(c4 + 3, row)) = f2bf(vf.w);
    }
    __syncthreads();
    f32x4 sacc[4];
    #pragma unroll
    for (int c = 0; c < 4; ++c) {
      sacc[c] = (f32x4){0.f, 0.f, 0.f, 0.f};
      #pragma unroll
      for (int s = 0; s < 2; ++s) {
        bf16x8 kb2 = *(const bf16x8*)((const char*)lK + swz(c * 16 + lr, s * 32 + lg * 8));
        sacc[c] = __builtin_amdgcn_mfma_f32_16x16x32_bf16(qa[s], kb2, sacc[c], 0, 0, 0);
      }
    }
    float mt[4], alpha[4];
    #pragma unroll
    for (int r = 0; r < 4; ++r) {
      float mm = fmaxf(fmaxf(sacc[0][r], sacc[1][r]), fmaxf(sacc[2][r], sacc[3][r]));
      mm = fmaxf(mm, __shfl_xor(mm, 1));
      mm = fmaxf(mm, __shfl_xor(mm, 2));
      mm = fmaxf(mm, __shfl_xor(mm, 4));
      mm = fmaxf(mm, __shfl_xor(mm, 8));
      mt[r] = fmaxf(mrow[r], mm);
      alpha[r] = __expf(mrow[r] - mt[r]);
      mrow[r] = mt[r];
    }
    #pragma unroll
    for (int c = 0; c < 4; ++c)
      #pragma unroll
      for (int r = 0; r < 4; ++r) sacc[c][r] = __expf(sacc[c][r] - mt[r]);
    #pragma unroll
    for (int r = 0; r < 4; ++r) {
      float sum = sacc[0][r] + sacc[1][r] + sacc[2][r] + sacc[3][r];
      sum += __shfl_xor(sum, 1);
      sum += __shfl_xor(sum, 2);
      sum += __shfl_xor(sum, 4);
      sum += __shfl_xor(sum, 8);
      lrow[r] = lrow[r] * alpha[r] + sum;
      #pragma unroll
      for (int e = 0; e < 4; ++e) yacc[e][r] *= alpha[r];
    }
    unsigned short* pw = lP[wave];
    #pragma unroll
    for (int c = 0; c < 4; ++c)
      #pragma unroll
      for (int r = 0; r < 4; ++r)
        *(unsigned short*)((char*)pw + swz(lg * 4 + r, c * 16 + lr)) = f2bf(sacc[c][r]);
    asm volatile("s_waitcnt lgkmcnt(0)" ::: "memory");
    #pragma unroll
    for (int s = 0; s < 2; ++s) {
      bf16x8 pa = *(const bf16x8*)((const char*)pw + swz(lr, s * 32 + lg * 8));
      #pragma unroll
      for (int e = 0; e < 4; ++e) {
        bf16x8 vb = *(const bf16x8*)((const char*)lV + swz(e * 16 + lr, s * 32 + lg * 8));
        yacc[e] = __builtin_amdgcn_mfma_f32_16x16x32_bf16(pa, vb, yacc[e], 0, 0, 0);
      }
    }
  }
  unsigned short* pw = lP[wave];
  #pragma unroll
  for (int e = 0; e < 4; ++e)
    #pragma unroll
    for (int r = 0; r < 4; ++r)
      *(unsigned short*)((char*)pw + swz(lg * 4 + r, e * 16 + lr)) = f2bf(yacc[e][r] / lrow[r]);
  asm volatile("s_waitcnt lgkmcnt(0)" ::: "memory");
  f32x4 oacc[4];
  #pragma unroll
  for (int c = 0; c < 4; ++c) oacc[c] = (f32x4){0.f, 0.f, 0.f, 0.f};
  #pragma unroll
  for (int s = 0; s < 2; ++s) {
    bf16x8 ya = *(const bf16x8*)((const char*)pw + swz(lr, s * 32 + lg * 8));
    #pragma unroll
    for (int c = 0; c < 4; ++c) {
      const float* wp = wg + (size_t)(c * 16 + lr) * 64 + s * 32 + lg * 8;
      float4 f0 = *(const float4*)wp;
      float4 f1 = *(const float4*)(wp + 4);
      bf16x8 wb;
      wb[0]=(short)f2bf(f0.x); wb[1]=(short)f2bf(f0.y); wb[2]=(short)f2bf(f0.z); wb[3]=(short)f2bf(f0.w);
      wb[4]=(short)f2bf(f1.x); wb[5]=(short)f2bf(f1.y); wb[6]=(short)f2bf(f1.z); wb[7]=(short)f2bf(f1.w);
      oacc[c] = __builtin_amdgcn_mfma_f32_16x16x32_bf16(ya, wb, oacc[c], 0, 0, 0);
    }
  }
  float* op = og + head_off + (size_t)(qt * 64 + wave * 16) * 64;
  #pragma unroll
  for (int c = 0; c < 4; ++c) {
    float bias = bg[c * 16 + lr];
    #pragma unroll
    for (int r = 0; r < 4; ++r)
      op[(size_t)(lg * 4 + r) * 64 + c * 16 + lr] = oacc[c][r] + bias;
  }
}

extern "C" void kernel_launch(void* const* d_in, const int* in_sizes, int n_in,
                              void* d_out, int out_size, void* d_ws, size_t ws_size,
                              hipStream_t stream) {
  const float* q = (const float*)d_in[0];
  const float* k = (const float*)d_in[1];
  const float* v = (const float*)d_in[2];
  const float* w = (const float*)d_in[3];
  const float* b = (const float*)d_in[4];
  float* out = (float*)d_out;

  const size_t tensor_elems = (size_t)NHEAD * HEAD_ELEMS;           // 8,388,608
  const size_t need = 2ull * tensor_elems * sizeof(unsigned short); // ~33.6 MB

  if (ws_size >= need) {
    unsigned short* kws = (unsigned short*)d_ws;
    unsigned short* vws = kws + tensor_elems;
    prep<<<4096, 256, 0, stream>>>(k, v, kws, vws);
    attn_reg2<<<512, 256, 0, stream>>>(q, kws, vws, w, b, out);
  } else {
    attn_proj_kernel<<<64 * 32, 256, 0, stream>>>(q, k, v, w, b, out);
  }
}